// Round 7
// baseline (768.222 us; speedup 1.0000x reference)
//
#include <hip/hip_runtime.h>
#include <hip/hip_bf16.h>
#include <stdint.h>

// Problem constants
#define LQ    4096
#define DMOD  768
#define IMGD  1408
#define TT    2
#define MM    6
#define LL    3
#define PP    4
#define DH    128
#define STOT  25039          // 28^3 + 14^3 + 7^3
#define OFFC  432
#define AWC   144
#define PROJC 576
#define NSAMP 24
#define NCORN 192

typedef __attribute__((ext_vector_type(8))) __bf16 bf16x8;
typedef __attribute__((ext_vector_type(4))) float  f32x4;

__device__ __forceinline__ void gl_lds16(const void* g, void* l) {
    __builtin_amdgcn_global_load_lds(
        (const __attribute__((address_space(1))) void*)g,
        (__attribute__((address_space(3))) void*)l, 16, 0, 0);
}

// ---------------------------------------------------------------------------
// Prep: WT[n][k] = (bf16) W[k][n]
// ---------------------------------------------------------------------------
__global__ __launch_bounds__(256) void cvt_transpose(
    const float* __restrict__ W, __bf16* __restrict__ WT, int K, int N)
{
    __shared__ float tile[32][33];
    const int k0 = blockIdx.x * 32, n0 = blockIdx.y * 32;
    const int c = threadIdx.x & 31, r8 = threadIdx.x >> 5;
    #pragma unroll
    for (int i = 0; i < 4; ++i) {
        int r = r8 + i * 8;
        int k = k0 + r, n = n0 + c;
        tile[r][c] = (k < K && n < N) ? W[(size_t)k * N + n] : 0.f;
    }
    __syncthreads();
    #pragma unroll
    for (int i = 0; i < 4; ++i) {
        int r = r8 + i * 8;
        int n = n0 + r, k = k0 + c;
        if (n < N && k < K) WT[(size_t)n * K + k] = (__bf16)tile[c][r];
    }
}

__global__ void concat_bias(const float* __restrict__ boff,
                            const float* __restrict__ ba,
                            float* __restrict__ bcat)
{
    int i = blockIdx.x * blockDim.x + threadIdx.x;
    if (i < PROJC) bcat[i] = (i < OFFC) ? boff[i] : ba[i - OFFC];
}

// ---------------------------------------------------------------------------
// Bulk f32 -> bf16 convert (BW-bound). n8 = elements/8, exact.
// ---------------------------------------------------------------------------
__global__ __launch_bounds__(256) void cvt_bf16_kernel(
    const float* __restrict__ in, __bf16* __restrict__ out, int n8)
{
    const int stride = gridDim.x * blockDim.x;
    for (int i = blockIdx.x * blockDim.x + threadIdx.x; i < n8; i += stride) {
        const float4* p = (const float4*)(in + (size_t)i * 8);
        float4 v0 = p[0], v1 = p[1];
        bf16x8 o;
        o[0] = (__bf16)v0.x; o[1] = (__bf16)v0.y;
        o[2] = (__bf16)v0.z; o[3] = (__bf16)v0.w;
        o[4] = (__bf16)v1.x; o[5] = (__bf16)v1.y;
        o[6] = (__bf16)v1.z; o[7] = (__bf16)v1.w;
        *(bf16x8*)(out + (size_t)i * 8) = o;
    }
}

// ---------------------------------------------------------------------------
// KS=4 split-K reduce: outp[e] = sum_s parts[s*total+e] + bias[e % N]
// ---------------------------------------------------------------------------
__global__ __launch_bounds__(256) void reduce_ksplit(
    const float* __restrict__ parts, const float* __restrict__ bias,
    float* __restrict__ outp, int N, int total)
{
    const size_t stride = (size_t)gridDim.x * blockDim.x * 4;
    for (size_t e = ((size_t)blockIdx.x * blockDim.x + threadIdx.x) * 4;
         e < (size_t)total; e += stride) {
        float4 s0 = *(const float4*)(parts + e);
        float4 s1 = *(const float4*)(parts + e + (size_t)total);
        float4 s2 = *(const float4*)(parts + e + 2 * (size_t)total);
        float4 s3 = *(const float4*)(parts + e + 3 * (size_t)total);
        const int col = (int)(e % (size_t)N);
        float4 r;
        r.x = s0.x + s1.x + s2.x + s3.x + bias[col + 0];
        r.y = s0.y + s1.y + s2.y + s3.y + bias[col + 1];
        r.z = s0.z + s1.z + s2.z + s3.z + bias[col + 2];
        r.w = s0.w + s1.w + s2.w + s3.w + bias[col + 3];
        *(float4*)(outp + e) = r;
    }
}

// ---------------------------------------------------------------------------
// MFMA GEMM, double-buffered single-barrier K-loop.
// C(MxN) = A(MxK) @ BT(NxK)^T + bias
// 128x128 tile, BK=32, 4 waves, wave 64x64 (4x4 of 16x16x32 bf16 MFMA).
// AF32=1: A is f32, converted in VGPRs during staging (ds_write path).
// AF32=0: A is bf16, staged via global_load_lds (rows must be readable).
// SWZ>0: 1-D grid; SWZ N-blocks of each M-panel co-located on one XCD.
//   REQUIRES (gridDim.x/8) % SWZ == 0 for bijectivity.
// SPLITK>1: blockIdx.z = K-chunk; f32 partials to Cp + z*M*N, no bias.
// B rows beyond N must be readable (ws layout guarantees slack).
// ---------------------------------------------------------------------------
template<int AF32, int OUT_BF16, int SWZ, int SPLITK = 1>
__global__ __launch_bounds__(256, 3) void gemm_mfma(
    const void* __restrict__ Ap, const __bf16* __restrict__ BT,
    const float* __restrict__ bias, void* __restrict__ Cp,
    int M, int N, int K)
{
    __shared__ __bf16 As[2][128][32];   // 16 KB
    __shared__ __bf16 Bs[2][128][32];   // 16 KB

    const int tid  = threadIdx.x;
    const int lane = tid & 63;
    const int wave = tid >> 6;
    const int wm = (wave & 1) * 64;
    const int wn = (wave >> 1) * 64;

    int bx, by;
    if constexpr (SWZ > 0) {
        const int bid = blockIdx.x;
        const int xcd = bid & 7;
        const int slot = bid >> 3;
        const int ppx = (gridDim.x >> 3) / SWZ;   // panels per XCD
        const int pix = slot / SWZ;
        bx = slot - pix * SWZ;
        by = xcd * ppx + pix;
    } else {
        bx = blockIdx.x; by = blockIdx.y;
    }
    const int row0 = by * 128;
    const int col0 = bx * 128;

    // split-K chunk
    const int kLen = (SPLITK > 1) ? (K / SPLITK) : K;
    const int k0   = (SPLITK > 1) ? ((int)blockIdx.z * kLen) : 0;
    float* Cpart = (float*)Cp;
    if constexpr (SPLITK > 1) Cpart += (size_t)blockIdx.z * ((size_t)M * N);

    const int fr = lane & 15;
    const int kq = lane >> 4;

    const int sr  = tid >> 1;          // AF32: row
    const int kk0 = (tid & 1) * 16;    // AF32: k-half

    float f[16];

    auto stageB = [&](int ki, int buf) {
        #pragma unroll
        for (int j = 0; j < 2; ++j) {
            const int g   = wave * 128 + j * 64 + lane;
            const int row = g >> 2, cir = g & 3;
            const __bf16* src = BT + (size_t)(col0 + row) * K + k0 + ki * 32 + cir * 8;
            gl_lds16(src, (char*)&Bs[buf][0][0] + (size_t)(wave * 128 + j * 64) * 16);
        }
    };
    auto stageA_lds = [&](int ki, int buf) {
        const __bf16* A = (const __bf16*)Ap;
        #pragma unroll
        for (int j = 0; j < 2; ++j) {
            const int g   = wave * 128 + j * 64 + lane;
            const int row = g >> 2, cir = g & 3;
            const __bf16* src = A + (size_t)(row0 + row) * K + k0 + ki * 32 + cir * 8;
            gl_lds16(src, (char*)&As[buf][0][0] + (size_t)(wave * 128 + j * 64) * 16);
        }
    };
    auto loadA_f32 = [&](int ki) {
        const float* A = (const float*)Ap;
        const int gm = row0 + sr;
        if (gm < M) {
            const float4* ap = (const float4*)(A + (size_t)gm * K + k0 + ki * 32 + kk0);
            #pragma unroll
            for (int i = 0; i < 4; ++i) {
                float4 v = ap[i];
                f[i*4+0] = v.x; f[i*4+1] = v.y; f[i*4+2] = v.z; f[i*4+3] = v.w;
            }
        } else {
            #pragma unroll
            for (int i = 0; i < 16; ++i) f[i] = 0.f;
        }
    };
    auto writeA = [&](int buf) {
        bf16x8 v0, v1;
        #pragma unroll
        for (int i = 0; i < 8; ++i) { v0[i] = (__bf16)f[i]; v1[i] = (__bf16)f[i+8]; }
        *(bf16x8*)&As[buf][sr][kk0]     = v0;
        *(bf16x8*)&As[buf][sr][kk0 + 8] = v1;
    };

    f32x4 acc[4][4] = {};
    const int nk = kLen >> 5;

    stageB(0, 0);
    if constexpr (AF32) { loadA_f32(0); writeA(0); }
    else                { stageA_lds(0, 0); }

    for (int i = 0; i < nk; ++i) {
        __syncthreads();
        const int cur = i & 1, nxt = cur ^ 1;
        const bool more = (i + 1) < nk;

        if (more) {
            stageB(i + 1, nxt);
            if constexpr (AF32) loadA_f32(i + 1);
            else                stageA_lds(i + 1, nxt);
        }

        bf16x8 a[4], b[4];
        #pragma unroll
        for (int mt = 0; mt < 4; ++mt) a[mt] = *(const bf16x8*)&As[cur][wm + mt*16 + fr][kq * 8];
        #pragma unroll
        for (int nt = 0; nt < 4; ++nt) b[nt] = *(const bf16x8*)&Bs[cur][wn + nt*16 + fr][kq * 8];
        #pragma unroll
        for (int mt = 0; mt < 4; ++mt)
            #pragma unroll
            for (int nt = 0; nt < 4; ++nt)
                acc[mt][nt] = __builtin_amdgcn_mfma_f32_16x16x32_bf16(
                    a[mt], b[nt], acc[mt][nt], 0, 0, 0);

        if constexpr (AF32) { if (more) writeA(nxt); }
    }

    // epilogue: C/D layout col=lane&15, row=(lane>>4)*4+reg
    const int col = lane & 15;
    const int rq  = (lane >> 4) * 4;
    #pragma unroll
    for (int mt = 0; mt < 4; ++mt) {
        #pragma unroll
        for (int r = 0; r < 4; ++r) {
            const int gm = row0 + wm + mt*16 + rq + r;
            if (gm >= M) continue;
            #pragma unroll
            for (int nt = 0; nt < 4; ++nt) {
                const int gn = col0 + wn + nt*16 + col;
                if (gn < N) {
                    if constexpr (SPLITK > 1) {
                        Cpart[(size_t)gm * N + gn] = acc[mt][nt][r];
                    } else {
                        float v = acc[mt][nt][r] + bias[gn];
                        if constexpr (OUT_BF16)
                            ((__bf16*)Cp)[(size_t)gm * N + gn] = (__bf16)v;
                        else
                            ((float*)Cp)[(size_t)gm * N + gn] = v;
                    }
                }
            }
        }
    }
}

// ---------------------------------------------------------------------------
// Fused softmax + trilinear sampling. One wave per (q, m); 4 waves/block.
// Lane = (h = corner parity, c = channel quad): uint2 gather (4 channels).
// ---------------------------------------------------------------------------
__global__ __launch_bounds__(256) void sample_kernel(
    const float* __restrict__ refp,   // (LQ,3)
    const float* __restrict__ proj,   // (LQ,576): [0,432)=off, [432,576)=logits
    const __bf16* __restrict__ vbuf,  // (T,STOT,768) bf16
    __bf16* __restrict__ attn)        // (LQ,768) bf16
{
    const int wave = threadIdx.x >> 6;
    const int lane = threadIdx.x & 63;
    const int q = blockIdx.x * 4 + wave;
    const int m = blockIdx.y;

    __shared__ float    s_aw[4][NSAMP];
    __shared__ float    s_w[4][NCORN];
    __shared__ uint32_t s_o[4][NCORN];

    if (lane < NSAMP)
        s_aw[wave][lane] = proj[(size_t)q * PROJC + OFFC + m * NSAMP + lane];
    __syncthreads();

    if (lane < NSAMP) {
        float mx = -1e30f;
        #pragma unroll
        for (int i = 0; i < NSAMP; ++i) mx = fmaxf(mx, s_aw[wave][i]);
        float sum = 0.f;
        #pragma unroll
        for (int i = 0; i < NSAMP; ++i) sum += __expf(s_aw[wave][i] - mx);
        const float aww = __expf(s_aw[wave][lane] - mx) / sum;

        const int t = lane / 12;
        const int r = lane - t * 12;
        const int l = r >> 2;
        const int   Dl    = (l == 0) ? 28 : (l == 1) ? 14 : 7;
        const int   start = (l == 0) ? 0  : (l == 1) ? 21952 : 24696;
        const float fD    = (float)Dl;
        const int   base  = t * STOT + start;

        const float* op = proj + (size_t)q * PROJC + m * 72 + lane * 3;
        const float rx = refp[q*3+0], ry = refp[q*3+1], rz = refp[q*3+2];
        float x = rx * fD + op[0] - 0.5f;
        float y = ry * fD + op[1] - 0.5f;
        float z = rz * fD + op[2] - 0.5f;
        float xf = floorf(x), yf = floorf(y), zf = floorf(z);
        float fx = x - xf, fy = y - yf, fz = z - zf;
        int x0 = (int)xf, y0 = (int)yf, z0 = (int)zf;
        float wx[2] = {1.f - fx, fx}, wy[2] = {1.f - fy, fy}, wz[2] = {1.f - fz, fz};
        #pragma unroll
        for (int cc = 0; cc < 8; ++cc) {
            int dx = cc & 1, dy = (cc >> 1) & 1, dz = cc >> 2;
            int xi = x0 + dx, yi = y0 + dy, zi = z0 + dz;
            bool ok = (xi >= 0) & (xi < Dl) & (yi >= 0) & (yi < Dl) &
                      (zi >= 0) & (zi < Dl);
            float    w   = ok ? aww * wx[dx] * wy[dy] * wz[dz] : 0.f;
            uint32_t off = ok ? (uint32_t)(base + (zi * Dl + yi) * Dl + xi) * (768u * 2u) : 0u;
            s_w[wave][lane * 8 + cc] = w;
            s_o[wave][lane * 8 + cc] = off;
        }
    }
    __syncthreads();

    const int h = lane >> 5;          // corner parity
    const int c = lane & 31;          // channel quad
    const char* vb = (const char*)vbuf + ((size_t)m * 128 + c * 4) * 2;
    float a0 = 0.f, a1 = 0.f, a2 = 0.f, a3 = 0.f;
    #pragma unroll 4
    for (int i = 0; i < NCORN / 2; ++i) {
        const float    w   = s_w[wave][2 * i + h];
        const uint32_t off = s_o[wave][2 * i + h];
        const uint2 u = *(const uint2*)(vb + off);
        a0 += w * __uint_as_float(u.x << 16);
        a1 += w * __uint_as_float(u.x & 0xffff0000u);
        a2 += w * __uint_as_float(u.y << 16);
        a3 += w * __uint_as_float(u.y & 0xffff0000u);
    }
    a0 += __shfl_xor(a0, 32);
    a1 += __shfl_xor(a1, 32);
    a2 += __shfl_xor(a2, 32);
    a3 += __shfl_xor(a3, 32);

    if (h == 0) {
        union { __bf16 hh[4]; uint2 u; } pk;
        pk.hh[0] = (__bf16)a0; pk.hh[1] = (__bf16)a1;
        pk.hh[2] = (__bf16)a2; pk.hh[3] = (__bf16)a3;
        *(uint2*)((char*)attn + ((size_t)q * DMOD + m * 128 + c * 4) * 2) = pk.u;
    }
}

// ---------------------------------------------------------------------------
extern "C" void kernel_launch(void* const* d_in, const int* in_sizes, int n_in,
                              void* d_out, int out_size, void* d_ws, size_t ws_size,
                              hipStream_t stream) {
    const float* query = (const float*)d_in[0];
    const float* refp  = (const float*)d_in[1];
    const float* value = (const float*)d_in[2];
    const float* Wv    = (const float*)d_in[3];
    const float* bv    = (const float*)d_in[4];
    const float* Woff  = (const float*)d_in[5];
    const float* boff  = (const float*)d_in[6];
    const float* Wa    = (const float*)d_in[7];
    const float* ba    = (const float*)d_in[8];
    const float* Wo    = (const float*)d_in[9];
    const float* bo    = (const float*)d_in[10];
    float* out = (float*)d_out;

    const int    Mv      = TT * STOT;                      // 50078
    const size_t SZ_ABF  = (size_t)Mv * IMGD * 2;          // 141,019,648 (bf16 A for G1;
                                                           // reused as split-K partials)
    const size_t SZ_VBUF = (size_t)TT * STOT * DMOD * 2;   //  76,919,808
    const size_t SZ_PROJ = (size_t)LQ * PROJC * 4;         //   9,437,184
    const size_t SZ_ATTN = (size_t)LQ * DMOD * 2;          //   6,291,456
    const size_t SZ_WVT  = (size_t)IMGD * DMOD * 2;        //   2,162,688
    const size_t SZ_WCAT = (size_t)PROJC * DMOD * 2;       //     884,736
    const size_t SZ_WOT  = (size_t)DMOD * DMOD * 2;        //   1,179,648
    const size_t SZ_BCAT = (size_t)PROJC * 4;

    const size_t need_cvt = SZ_ABF + SZ_VBUF + SZ_PROJ + SZ_ATTN +
                            SZ_WVT + SZ_WCAT + SZ_WOT + SZ_BCAT;
    const bool use_cvtA = (ws_size >= need_cvt);

    char* p = (char*)d_ws;
    __bf16* abf = nullptr;
    if (use_cvtA) { abf = (__bf16*)p; p += SZ_ABF; }  // first: OOB A-panel rows
                                                      // land in vbuf (readable)
    __bf16* vbuf  = (__bf16*)p; p += SZ_VBUF;
    float*  proj  = (float*)p;  p += SZ_PROJ;
    __bf16* attn  = (__bf16*)p; p += SZ_ATTN;
    __bf16* wvt   = (__bf16*)p; p += SZ_WVT;
    __bf16* wcatT = (__bf16*)p; p += SZ_WCAT;   // OOB B-rows spill into woT: readable
    __bf16* woT   = (__bf16*)p; p += SZ_WOT;
    float*  bcat  = (float*)p;

    // ---- weight preps
    cvt_transpose<<<dim3((IMGD+31)/32, (DMOD+31)/32), 256, 0, stream>>>(Wv, wvt, IMGD, DMOD);
    cvt_transpose<<<dim3((DMOD+31)/32, (OFFC+31)/32), 256, 0, stream>>>(Woff, wcatT, DMOD, OFFC);
    cvt_transpose<<<dim3((DMOD+31)/32, (AWC +31)/32), 256, 0, stream>>>(Wa, wcatT + (size_t)OFFC * DMOD, DMOD, AWC);
    cvt_transpose<<<dim3((DMOD+31)/32, (DMOD+31)/32), 256, 0, stream>>>(Wo, woT, DMOD, DMOD);
    concat_bias<<<dim3(3), 256, 0, stream>>>(boff, ba, bcat);

    if (use_cvtA) {
        // ---- A -> bf16, split into 2 dispatches (profiling bisection)
        const int n8  = (int)(((size_t)Mv * IMGD) / 8);    // 8,813,728
        const int n8h = n8 / 2;
        cvt_bf16_kernel<<<dim3(1024), 256, 0, stream>>>(value, abf, n8h);
        cvt_bf16_kernel<<<dim3(1024), 256, 0, stream>>>(
            value + (size_t)n8h * 8, abf + (size_t)n8h * 8, n8 - n8h);

        // ---- G1: vbuf = abf @ wvt^T + bv (bf16 out), split into 2 M-halves
        // half-1: 192 panels (24576 rows), grid 1152 (1152/8=144, 144%6==0)
        // half-2: 200 panels (25502 rows), grid 1200 (150%6==0);
        //   OOB A rows (<=98) read past abf into vbuf: readable.
        const int M1 = 192 * 128;            // 24576
        const int M2 = Mv - M1;              // 25502
        gemm_mfma<0, 1, 6><<<dim3(1152), 256, 0, stream>>>(
            abf, wvt, bv, vbuf, M1, DMOD, IMGD);
        gemm_mfma<0, 1, 6><<<dim3(1200), 256, 0, stream>>>(
            abf + (size_t)M1 * IMGD, wvt, bv,
            vbuf + (size_t)M1 * DMOD, M2, DMOD, IMGD);

        // ---- G2: proj = query @ [Woff|Wa] + bcat, split-K=4
        // partials in abf region (dead after G1): 4 x 4096 x 576 f32 = 37.7 MB
        float* g2p = (float*)abf;
        gemm_mfma<1, 0, 0, 4><<<dim3(5, 32, 4), 256, 0, stream>>>(
            query, wcatT, nullptr, g2p, LQ, PROJC, DMOD);
        reduce_ksplit<<<dim3(1024), 256, 0, stream>>>(
            g2p, bcat, proj, PROJC, LQ * PROJC);

        // ---- sampling + softmax + head accumulation (bf16 out)
        sample_kernel<<<dim3(LQ / 4, MM), 256, 0, stream>>>(refp, proj, vbuf, attn);

        // ---- G3: out = attn @ Wo + bo, split-K=4
        float* g3p = (float*)abf;
        gemm_mfma<0, 0, 0, 4><<<dim3(6, 32, 4), 256, 0, stream>>>(
            attn, woT, nullptr, g3p, LQ, DMOD, DMOD);
        reduce_ksplit<<<dim3(1024), 256, 0, stream>>>(
            g3p, bo, out, DMOD, LQ * DMOD);
    } else {
        // fallback: original single-kernel paths (no abf workspace)
        gemm_mfma<1, 1, 6><<<dim3(2352), 256, 0, stream>>>(
            value, wvt, bv, vbuf, Mv, DMOD, IMGD);
        gemm_mfma<1, 0, 0><<<dim3((PROJC + 127) / 128, LQ / 128), 256, 0, stream>>>(
            query, wcatT, bcat, proj, LQ, PROJC, DMOD);
        sample_kernel<<<dim3(LQ / 4, MM), 256, 0, stream>>>(refp, proj, vbuf, attn);
        gemm_mfma<0, 0, 0><<<dim3(DMOD / 128, LQ / 128), 256, 0, stream>>>(
            attn, woT, bo, out, LQ, DMOD, DMOD);
    }
}

// Round 9
// 729.277 us; speedup vs baseline: 1.0534x; 1.0534x over previous
//
#include <hip/hip_runtime.h>
#include <hip/hip_bf16.h>
#include <stdint.h>

// Problem constants
#define LQ    4096
#define DMOD  768
#define IMGD  1408
#define TT    2
#define MM    6
#define LL    3
#define PP    4
#define DH    128
#define STOT  25039          // 28^3 + 14^3 + 7^3
#define OFFC  432
#define AWC   144
#define PROJC 576
#define NSAMP 24
#define NCORN 192

typedef __attribute__((ext_vector_type(8))) __bf16 bf16x8;
typedef __attribute__((ext_vector_type(4))) float  f32x4;

__device__ __forceinline__ void gl_lds16(const void* g, void* l) {
    __builtin_amdgcn_global_load_lds(
        (const __attribute__((address_space(1))) void*)g,
        (__attribute__((address_space(3))) void*)l, 16, 0, 0);
}

// ---------------------------------------------------------------------------
// Prep: WT[n][k] = (bf16) W[k][n]
// ---------------------------------------------------------------------------
__global__ __launch_bounds__(256) void cvt_transpose(
    const float* __restrict__ W, __bf16* __restrict__ WT, int K, int N)
{
    __shared__ float tile[32][33];
    const int k0 = blockIdx.x * 32, n0 = blockIdx.y * 32;
    const int c = threadIdx.x & 31, r8 = threadIdx.x >> 5;
    #pragma unroll
    for (int i = 0; i < 4; ++i) {
        int r = r8 + i * 8;
        int k = k0 + r, n = n0 + c;
        tile[r][c] = (k < K && n < N) ? W[(size_t)k * N + n] : 0.f;
    }
    __syncthreads();
    #pragma unroll
    for (int i = 0; i < 4; ++i) {
        int r = r8 + i * 8;
        int n = n0 + r, k = k0 + c;
        if (n < N && k < K) WT[(size_t)n * K + k] = (__bf16)tile[c][r];
    }
}

__global__ void concat_bias(const float* __restrict__ boff,
                            const float* __restrict__ ba,
                            float* __restrict__ bcat)
{
    int i = blockIdx.x * blockDim.x + threadIdx.x;
    if (i < PROJC) bcat[i] = (i < OFFC) ? boff[i] : ba[i - OFFC];
}

// ---------------------------------------------------------------------------
// Bulk f32 -> bf16 convert (BW-bound). n8 = elements/8, exact.
// ---------------------------------------------------------------------------
__global__ __launch_bounds__(256) void cvt_bf16_kernel(
    const float* __restrict__ in, __bf16* __restrict__ out, int n8)
{
    const int stride = gridDim.x * blockDim.x;
    for (int i = blockIdx.x * blockDim.x + threadIdx.x; i < n8; i += stride) {
        const float4* p = (const float4*)(in + (size_t)i * 8);
        float4 v0 = p[0], v1 = p[1];
        bf16x8 o;
        o[0] = (__bf16)v0.x; o[1] = (__bf16)v0.y;
        o[2] = (__bf16)v0.z; o[3] = (__bf16)v0.w;
        o[4] = (__bf16)v1.x; o[5] = (__bf16)v1.y;
        o[6] = (__bf16)v1.z; o[7] = (__bf16)v1.w;
        *(bf16x8*)(out + (size_t)i * 8) = o;
    }
}

// ---------------------------------------------------------------------------
// KS=4 split-K reduce: outp[e] = sum_s parts[s*total+e] + bias[e % N]
// ---------------------------------------------------------------------------
__global__ __launch_bounds__(256) void reduce_ksplit(
    const float* __restrict__ parts, const float* __restrict__ bias,
    float* __restrict__ outp, int N, int total)
{
    const size_t stride = (size_t)gridDim.x * blockDim.x * 4;
    for (size_t e = ((size_t)blockIdx.x * blockDim.x + threadIdx.x) * 4;
         e < (size_t)total; e += stride) {
        float4 s0 = *(const float4*)(parts + e);
        float4 s1 = *(const float4*)(parts + e + (size_t)total);
        float4 s2 = *(const float4*)(parts + e + 2 * (size_t)total);
        float4 s3 = *(const float4*)(parts + e + 3 * (size_t)total);
        const int col = (int)(e % (size_t)N);
        float4 r;
        r.x = s0.x + s1.x + s2.x + s3.x + bias[col + 0];
        r.y = s0.y + s1.y + s2.y + s3.y + bias[col + 1];
        r.z = s0.z + s1.z + s2.z + s3.z + bias[col + 2];
        r.w = s0.w + s1.w + s2.w + s3.w + bias[col + 3];
        *(float4*)(outp + e) = r;
    }
}

// ---------------------------------------------------------------------------
// MFMA GEMM, double-buffered single-barrier K-loop.
// C(MxN) = A(MxK) @ BT(NxK)^T + bias
// 128x128 tile, BK=32, 4 waves, wave 64x64 (4x4 of 16x16x32 bf16 MFMA).
// AF32=1: A is f32, converted in VGPRs during staging (ds_write path).
// AF32=0: A is bf16, staged via global_load_lds (rows must be readable).
// SWZ>0: 1-D grid; SWZ N-blocks of each M-panel co-located on one XCD.
//   REQUIRES (gridDim.x/8) % SWZ == 0 for bijectivity.
// SPLITK>1: blockIdx.z = K-chunk; f32 partials to Cp + z*M*N, no bias.
// B rows beyond N must be readable (ws layout guarantees slack).
// ---------------------------------------------------------------------------
template<int AF32, int OUT_BF16, int SWZ, int SPLITK = 1>
__global__ __launch_bounds__(256, 3) void gemm_mfma(
    const void* __restrict__ Ap, const __bf16* __restrict__ BT,
    const float* __restrict__ bias, void* __restrict__ Cp,
    int M, int N, int K)
{
    __shared__ __bf16 As[2][128][32];   // 16 KB
    __shared__ __bf16 Bs[2][128][32];   // 16 KB

    const int tid  = threadIdx.x;
    const int lane = tid & 63;
    const int wave = tid >> 6;
    const int wm = (wave & 1) * 64;
    const int wn = (wave >> 1) * 64;

    int bx, by;
    if constexpr (SWZ > 0) {
        const int bid = blockIdx.x;
        const int xcd = bid & 7;
        const int slot = bid >> 3;
        const int ppx = (gridDim.x >> 3) / SWZ;   // panels per XCD
        const int pix = slot / SWZ;
        bx = slot - pix * SWZ;
        by = xcd * ppx + pix;
    } else {
        bx = blockIdx.x; by = blockIdx.y;
    }
    const int row0 = by * 128;
    const int col0 = bx * 128;

    // split-K chunk
    const int kLen = (SPLITK > 1) ? (K / SPLITK) : K;
    const int k0   = (SPLITK > 1) ? ((int)blockIdx.z * kLen) : 0;
    float* Cpart = (float*)Cp;
    if constexpr (SPLITK > 1) Cpart += (size_t)blockIdx.z * ((size_t)M * N);

    const int fr = lane & 15;
    const int kq = lane >> 4;

    const int sr  = tid >> 1;          // AF32: row
    const int kk0 = (tid & 1) * 16;    // AF32: k-half

    float f[16];

    auto stageB = [&](int ki, int buf) {
        #pragma unroll
        for (int j = 0; j < 2; ++j) {
            const int g   = wave * 128 + j * 64 + lane;
            const int row = g >> 2, cir = g & 3;
            const __bf16* src = BT + (size_t)(col0 + row) * K + k0 + ki * 32 + cir * 8;
            gl_lds16(src, (char*)&Bs[buf][0][0] + (size_t)(wave * 128 + j * 64) * 16);
        }
    };
    auto stageA_lds = [&](int ki, int buf) {
        const __bf16* A = (const __bf16*)Ap;
        #pragma unroll
        for (int j = 0; j < 2; ++j) {
            const int g   = wave * 128 + j * 64 + lane;
            const int row = g >> 2, cir = g & 3;
            const __bf16* src = A + (size_t)(row0 + row) * K + k0 + ki * 32 + cir * 8;
            gl_lds16(src, (char*)&As[buf][0][0] + (size_t)(wave * 128 + j * 64) * 16);
        }
    };
    auto loadA_f32 = [&](int ki) {
        const float* A = (const float*)Ap;
        const int gm = row0 + sr;
        if (gm < M) {
            const float4* ap = (const float4*)(A + (size_t)gm * K + k0 + ki * 32 + kk0);
            #pragma unroll
            for (int i = 0; i < 4; ++i) {
                float4 v = ap[i];
                f[i*4+0] = v.x; f[i*4+1] = v.y; f[i*4+2] = v.z; f[i*4+3] = v.w;
            }
        } else {
            #pragma unroll
            for (int i = 0; i < 16; ++i) f[i] = 0.f;
        }
    };
    auto writeA = [&](int buf) {
        bf16x8 v0, v1;
        #pragma unroll
        for (int i = 0; i < 8; ++i) { v0[i] = (__bf16)f[i]; v1[i] = (__bf16)f[i+8]; }
        *(bf16x8*)&As[buf][sr][kk0]     = v0;
        *(bf16x8*)&As[buf][sr][kk0 + 8] = v1;
    };

    f32x4 acc[4][4] = {};
    const int nk = kLen >> 5;

    stageB(0, 0);
    if constexpr (AF32) { loadA_f32(0); writeA(0); }
    else                { stageA_lds(0, 0); }

    for (int i = 0; i < nk; ++i) {
        __syncthreads();
        const int cur = i & 1, nxt = cur ^ 1;
        const bool more = (i + 1) < nk;

        if (more) {
            stageB(i + 1, nxt);
            if constexpr (AF32) loadA_f32(i + 1);
            else                stageA_lds(i + 1, nxt);
        }

        bf16x8 a[4], b[4];
        #pragma unroll
        for (int mt = 0; mt < 4; ++mt) a[mt] = *(const bf16x8*)&As[cur][wm + mt*16 + fr][kq * 8];
        #pragma unroll
        for (int nt = 0; nt < 4; ++nt) b[nt] = *(const bf16x8*)&Bs[cur][wn + nt*16 + fr][kq * 8];
        #pragma unroll
        for (int mt = 0; mt < 4; ++mt)
            #pragma unroll
            for (int nt = 0; nt < 4; ++nt)
                acc[mt][nt] = __builtin_amdgcn_mfma_f32_16x16x32_bf16(
                    a[mt], b[nt], acc[mt][nt], 0, 0, 0);

        if constexpr (AF32) { if (more) writeA(nxt); }
    }

    // epilogue: C/D layout col=lane&15, row=(lane>>4)*4+reg
    const int col = lane & 15;
    const int rq  = (lane >> 4) * 4;
    #pragma unroll
    for (int mt = 0; mt < 4; ++mt) {
        #pragma unroll
        for (int r = 0; r < 4; ++r) {
            const int gm = row0 + wm + mt*16 + rq + r;
            if (gm >= M) continue;
            #pragma unroll
            for (int nt = 0; nt < 4; ++nt) {
                const int gn = col0 + wn + nt*16 + col;
                if (gn < N) {
                    if constexpr (SPLITK > 1) {
                        Cpart[(size_t)gm * N + gn] = acc[mt][nt][r];
                    } else {
                        float v = acc[mt][nt][r] + bias[gn];
                        if constexpr (OUT_BF16)
                            ((__bf16*)Cp)[(size_t)gm * N + gn] = (__bf16)v;
                        else
                            ((float*)Cp)[(size_t)gm * N + gn] = v;
                    }
                }
            }
        }
    }
}

// ---------------------------------------------------------------------------
// Fused softmax + trilinear sampling. One wave per (q, m); 4 waves/block.
// Softmax over the 24 logits is wave-parallel via shfl_xor (1 exp/lane).
// Standard __syncthreads() between LDS-write and gather phases (safe).
// Lane = (h = corner parity, c = channel quad): uint2 gather (4 channels).
// ---------------------------------------------------------------------------
__global__ __launch_bounds__(256) void sample_kernel(
    const float* __restrict__ refp,   // (LQ,3)
    const float* __restrict__ proj,   // (LQ,576): [0,432)=off, [432,576)=logits
    const __bf16* __restrict__ vbuf,  // (T,STOT,768) bf16
    __bf16* __restrict__ attn)        // (LQ,768) bf16
{
    const int wave = threadIdx.x >> 6;
    const int lane = threadIdx.x & 63;
    const int q = blockIdx.x * 4 + wave;
    const int m = blockIdx.y;

    __shared__ float    s_w[4][NCORN];
    __shared__ uint32_t s_o[4][NCORN];

    // ---- wave-parallel softmax (lanes >= NSAMP contribute -inf / 0)
    float logit = -1e30f;
    if (lane < NSAMP)
        logit = proj[(size_t)q * PROJC + OFFC + m * NSAMP + lane];
    float mx = logit;
    #pragma unroll
    for (int d = 32; d > 0; d >>= 1) mx = fmaxf(mx, __shfl_xor(mx, d));
    const float ex = (lane < NSAMP) ? __expf(logit - mx) : 0.f;
    float sum = ex;
    #pragma unroll
    for (int d = 32; d > 0; d >>= 1) sum += __shfl_xor(sum, d);

    if (lane < NSAMP) {
        const float aww = ex / sum;

        const int t = lane / 12;
        const int r = lane - t * 12;
        const int l = r >> 2;
        const int   Dl    = (l == 0) ? 28 : (l == 1) ? 14 : 7;
        const int   start = (l == 0) ? 0  : (l == 1) ? 21952 : 24696;
        const float fD    = (float)Dl;
        const int   base  = t * STOT + start;

        const float* op = proj + (size_t)q * PROJC + m * 72 + lane * 3;
        const float rx = refp[q*3+0], ry = refp[q*3+1], rz = refp[q*3+2];
        float x = rx * fD + op[0] - 0.5f;
        float y = ry * fD + op[1] - 0.5f;
        float z = rz * fD + op[2] - 0.5f;
        float xf = floorf(x), yf = floorf(y), zf = floorf(z);
        float fx = x - xf, fy = y - yf, fz = z - zf;
        int x0 = (int)xf, y0 = (int)yf, z0 = (int)zf;
        float wx[2] = {1.f - fx, fx}, wy[2] = {1.f - fy, fy}, wz[2] = {1.f - fz, fz};
        #pragma unroll
        for (int cc = 0; cc < 8; ++cc) {
            int dx = cc & 1, dy = (cc >> 1) & 1, dz = cc >> 2;
            int xi = x0 + dx, yi = y0 + dy, zi = z0 + dz;
            bool ok = (xi >= 0) & (xi < Dl) & (yi >= 0) & (yi < Dl) &
                      (zi >= 0) & (zi < Dl);
            float    w   = ok ? aww * wx[dx] * wy[dy] * wz[dz] : 0.f;
            uint32_t off = ok ? (uint32_t)(base + (zi * Dl + yi) * Dl + xi) * (768u * 2u) : 0u;
            s_w[wave][lane * 8 + cc] = w;
            s_o[wave][lane * 8 + cc] = off;
        }
    }
    __syncthreads();

    const int h = lane >> 5;          // corner parity
    const int c = lane & 31;          // channel quad
    const char* vb = (const char*)vbuf + ((size_t)m * 128 + c * 4) * 2;
    float a0 = 0.f, a1 = 0.f, a2 = 0.f, a3 = 0.f;
    #pragma unroll 4
    for (int i = 0; i < NCORN / 2; ++i) {
        const float    w   = s_w[wave][2 * i + h];
        const uint32_t off = s_o[wave][2 * i + h];
        const uint2 u = *(const uint2*)(vb + off);
        a0 += w * __uint_as_float(u.x << 16);
        a1 += w * __uint_as_float(u.x & 0xffff0000u);
        a2 += w * __uint_as_float(u.y << 16);
        a3 += w * __uint_as_float(u.y & 0xffff0000u);
    }
    a0 += __shfl_xor(a0, 32);
    a1 += __shfl_xor(a1, 32);
    a2 += __shfl_xor(a2, 32);
    a3 += __shfl_xor(a3, 32);

    if (h == 0) {
        union { __bf16 hh[4]; uint2 u; } pk;
        pk.hh[0] = (__bf16)a0; pk.hh[1] = (__bf16)a1;
        pk.hh[2] = (__bf16)a2; pk.hh[3] = (__bf16)a3;
        *(uint2*)((char*)attn + ((size_t)q * DMOD + m * 128 + c * 4) * 2) = pk.u;
    }
}

// ---------------------------------------------------------------------------
extern "C" void kernel_launch(void* const* d_in, const int* in_sizes, int n_in,
                              void* d_out, int out_size, void* d_ws, size_t ws_size,
                              hipStream_t stream) {
    const float* query = (const float*)d_in[0];
    const float* refp  = (const float*)d_in[1];
    const float* value = (const float*)d_in[2];
    const float* Wv    = (const float*)d_in[3];
    const float* bv    = (const float*)d_in[4];
    const float* Woff  = (const float*)d_in[5];
    const float* boff  = (const float*)d_in[6];
    const float* Wa    = (const float*)d_in[7];
    const float* ba    = (const float*)d_in[8];
    const float* Wo    = (const float*)d_in[9];
    const float* bo    = (const float*)d_in[10];
    float* out = (float*)d_out;

    const int    Mv      = TT * STOT;                      // 50078
    const size_t SZ_ABF  = (size_t)Mv * IMGD * 2;          // 141,019,648 (bf16 A for G1;
                                                           // reused as split-K partials)
    const size_t SZ_VBUF = (size_t)TT * STOT * DMOD * 2;   //  76,919,808
    const size_t SZ_PROJ = (size_t)LQ * PROJC * 4;         //   9,437,184
    const size_t SZ_ATTN = (size_t)LQ * DMOD * 2;          //   6,291,456
    const size_t SZ_WVT  = (size_t)IMGD * DMOD * 2;        //   2,162,688
    const size_t SZ_WCAT = (size_t)PROJC * DMOD * 2;       //     884,736
    const size_t SZ_WOT  = (size_t)DMOD * DMOD * 2;        //   1,179,648
    const size_t SZ_BCAT = (size_t)PROJC * 4;

    const size_t need_cvt = SZ_ABF + SZ_VBUF + SZ_PROJ + SZ_ATTN +
                            SZ_WVT + SZ_WCAT + SZ_WOT + SZ_BCAT;
    const bool use_cvtA = (ws_size >= need_cvt);

    char* p = (char*)d_ws;
    __bf16* abf = nullptr;
    if (use_cvtA) { abf = (__bf16*)p; p += SZ_ABF; }  // first: OOB A-panel rows
                                                      // land in vbuf (readable)
    __bf16* vbuf  = (__bf16*)p; p += SZ_VBUF;
    float*  proj  = (float*)p;  p += SZ_PROJ;
    __bf16* attn  = (__bf16*)p; p += SZ_ATTN;
    __bf16* wvt   = (__bf16*)p; p += SZ_WVT;
    __bf16* wcatT = (__bf16*)p; p += SZ_WCAT;   // OOB B-rows spill into woT: readable
    __bf16* woT   = (__bf16*)p; p += SZ_WOT;
    float*  bcat  = (float*)p;

    // ---- weight preps
    cvt_transpose<<<dim3((IMGD+31)/32, (DMOD+31)/32), 256, 0, stream>>>(Wv, wvt, IMGD, DMOD);
    cvt_transpose<<<dim3((DMOD+31)/32, (OFFC+31)/32), 256, 0, stream>>>(Woff, wcatT, DMOD, OFFC);
    cvt_transpose<<<dim3((DMOD+31)/32, (AWC +31)/32), 256, 0, stream>>>(Wa, wcatT + (size_t)OFFC * DMOD, DMOD, AWC);
    cvt_transpose<<<dim3((DMOD+31)/32, (DMOD+31)/32), 256, 0, stream>>>(Wo, woT, DMOD, DMOD);
    concat_bias<<<dim3(3), 256, 0, stream>>>(boff, ba, bcat);

    if (use_cvtA) {
        // ---- A -> bf16 (grid 4096: more memory parallelism than 2048)
        const int n8 = (int)(((size_t)Mv * IMGD) / 8);     // 8,813,728
        cvt_bf16_kernel<<<dim3(4096), 256, 0, stream>>>(value, abf, n8);

        // ---- G1: vbuf = abf @ wvt^T + bv (bf16 out), single dispatch
        gemm_mfma<0, 1, 6><<<dim3(2352), 256, 0, stream>>>(
            abf, wvt, bv, vbuf, Mv, DMOD, IMGD);

        // ---- G2: proj = query @ [Woff|Wa] + bcat, split-K=4
        // partials in abf region (dead after G1): 4 x 4096 x 576 f32 = 37.7 MB
        float* g2p = (float*)abf;
        gemm_mfma<1, 0, 0, 4><<<dim3(5, 32, 4), 256, 0, stream>>>(
            query, wcatT, nullptr, g2p, LQ, PROJC, DMOD);
        reduce_ksplit<<<dim3(1024), 256, 0, stream>>>(
            g2p, bcat, proj, PROJC, LQ * PROJC);

        // ---- sampling + softmax + head accumulation (bf16 out)
        sample_kernel<<<dim3(LQ / 4, MM), 256, 0, stream>>>(refp, proj, vbuf, attn);

        // ---- G3: out = attn @ Wo + bo, split-K=4
        float* g3p = (float*)abf;
        gemm_mfma<0, 0, 0, 4><<<dim3(6, 32, 4), 256, 0, stream>>>(
            attn, woT, nullptr, g3p, LQ, DMOD, DMOD);
        reduce_ksplit<<<dim3(1024), 256, 0, stream>>>(
            g3p, bo, out, DMOD, LQ * DMOD);
    } else {
        // fallback: original single-kernel paths (no abf workspace)
        gemm_mfma<1, 1, 6><<<dim3(2352), 256, 0, stream>>>(
            value, wvt, bv, vbuf, Mv, DMOD, IMGD);
        gemm_mfma<1, 0, 0><<<dim3((PROJC + 127) / 128, LQ / 128), 256, 0, stream>>>(
            query, wcatT, bcat, proj, LQ, PROJC, DMOD);
        sample_kernel<<<dim3(LQ / 4, MM), 256, 0, stream>>>(refp, proj, vbuf, attn);
        gemm_mfma<0, 0, 0><<<dim3(DMOD / 128, LQ / 128), 256, 0, stream>>>(
            attn, woT, bo, out, LQ, DMOD, DMOD);
    }
}